// Round 20
// baseline (119.806 us; speedup 1.0000x reference)
//
#include <hip/hip_runtime.h>
#include <hip/hip_bf16.h>

typedef __attribute__((ext_vector_type(2))) float f32x2;
typedef __attribute__((ext_vector_type(4))) float f32x4;
typedef __attribute__((ext_vector_type(4))) unsigned int u32x4;
typedef __attribute__((ext_vector_type(8))) short s16x8;

#define B_  128
#define P_  196
#define E_  2048
#define D_  512
#define A_  512
#define M_  (B_*P_)   // 25088
#define MT  112       // m-rows per block -> 224 blocks

#define WAIT_LGKM0() asm volatile("s_waitcnt lgkmcnt(0)" ::: "memory")

// ---------------------------------------------------------------------------
// Kernel W: transpose + rne-bf16 + FRAGMENT-ORDER store (R17 layout, 32-wide
// kt records): WeTf[kt*16384 + nf*512 + (q*16+fr)*8 + j]
//   = bf16(We[kt*32+q*8+j][nf*16+fr]) — each 1KB record is one B-fragment.
// ---------------------------------------------------------------------------
__global__ void we_conv_kernel(const float* __restrict__ We,
                               unsigned short* __restrict__ WeTf) {
  __shared__ float tile[32][33];
  const int tx = threadIdx.x, ty = threadIdx.y;
  const int a0 = blockIdx.x * 32, e0 = blockIdx.y * 32;
  tile[ty][tx] = We[(e0 + ty) * A_ + a0 + tx];
  __syncthreads();
  const float v = tile[tx][ty];              // = We[e0+tx][a0+ty]
  const unsigned int u = __float_as_uint(v);
  const unsigned short r = (unsigned short)((u + 0x7fffu + ((u >> 16) & 1u)) >> 16);
  const int a = a0 + ty;                     // n-row 0..511
  const int kt = blockIdx.y;                 // K-tile (e = kt*32 + tx)
  const int q = tx >> 3, j = tx & 7;
  const int nf = a >> 4, fr = a & 15;
  WeTf[kt * 16384 + nf * 512 + (q * 16 + fr) * 8 + j] = r;
}

// ---------------------------------------------------------------------------
// Kernel A: att2pb[b][a] = decoder_hidden[b] @ Wd + bd[a] + be[a]  (fp32)
// ---------------------------------------------------------------------------
__global__ void att2_kernel(const float* __restrict__ h, const float* __restrict__ Wd,
                            const float* __restrict__ bd, const float* __restrict__ be,
                            float* __restrict__ att2pb) {
  const int b = blockIdx.x;
  const int t = threadIdx.x;  // 256
  __shared__ float hs[D_];
  hs[t] = h[b * D_ + t];
  hs[t + 256] = h[b * D_ + t + 256];
  __syncthreads();
  float a0 = 0.f, a1 = 0.f;
  for (int d = 0; d < D_; ++d) {
    const float hv = hs[d];
    a0 = fmaf(hv, Wd[d * A_ + t], a0);
    a1 = fmaf(hv, Wd[d * A_ + t + 256], a1);
  }
  att2pb[b * A_ + t] = a0 + bd[t] + be[t];
  att2pb[b * A_ + t + 256] = a1 + bd[t + 256] + be[t + 256];
}

// ---------------------------------------------------------------------------
__device__ inline unsigned pk2(float a, float b) {
  union { __hip_bfloat162 h; unsigned u; } cv;
  cv.h = __float22bfloat162_rn(make_float2(a, b));
  return cv.u;
}
__device__ inline u32x4 cvt8(const f32x4 lo, const f32x4 hi) {
  u32x4 r;
  r[0] = pk2(lo[0], lo[1]);
  r[1] = pk2(lo[2], lo[3]);
  r[2] = pk2(hi[0], hi[1]);
  r[3] = pk2(hi[2], hi[3]);
  return r;
}
__device__ __forceinline__ s16x8 ldsr(const unsigned short* p) {
  return *(const s16x8*)p;
}
#define MF(a, b, c) c = __builtin_amdgcn_mfma_f32_16x16x32_bf16(a, b, c, 0, 0, 0)

// ---------------------------------------------------------------------------
// Kernel B v19 == v18 + OOB fix: the A(it+2) prefetch is clamped to tile 31
// (at it=30, R18 read k-offset 2048 == E_ past the row end -> memory fault).
// Structure: B direct from L2 (fragment-order WeTf, ping-pong regs, reload
// after last use), A in LDS ring-3 at BK=64 -> 32 barriers.  16 waves,
// wave tile 112m x 32n, 224 blocks, LDS = 3 x 16 KB.
// ---------------------------------------------------------------------------
__launch_bounds__(1024, 4)
__global__ void score_kernel(const float* __restrict__ enc,
                             const unsigned short* __restrict__ WeTf,
                             const float* __restrict__ att2pb,
                             const float* __restrict__ Wf,
                             float* __restrict__ att_part) {
  __shared__ unsigned short Ahs[3][128 * 64];  // 3 x 16 KB ring (rows 112+ pad)

  const int bid = blockIdx.x;               // 0..223
  const int m0 = bid * MT;

  const int t = threadIdx.x;                // 0..1023
  const int lane = t & 63, w = t >> 6;      // 16 waves
  const int wn = w * 32;                    // wave n-origin

  // A staging: row ar = t>>3 (clamped to MT-1), 8 f32 at chunk t&7 -> 16B write
  const int ar = t >> 3, ac8 = t & 7;
  const int arc = ar < MT ? ar : MT - 1;
  const float* aptr = enc + (size_t)(m0 + arc) * E_ + ac8 * 8;
  const int awz = (ar * 64 + ac8 * 8) ^ ((ar & 7) << 3);   // shorts, 16B-aligned

  // B direct: frag (kt32, j) at bfp + kt32*16384 + j*512  (nf = w*2 + j)
  const unsigned short* bfp = WeTf + (w * 2) * 512 + lane * 8;

  // A fragment read offsets (64-wide rows, two k-halves)
  const int q = lane >> 4, fr = lane & 15;
  const int fx = (fr & 7) << 3;
  int fa[2][7];
#pragma unroll
  for (int ks = 0; ks < 2; ++ks)
#pragma unroll
    for (int i = 0; i < 7; ++i)
      fa[ks][i] = ((i * 16 + fr) * 64 + ks * 32 + q * 8) ^ fx;

  const f32x4 zero = {0.f, 0.f, 0.f, 0.f};
  f32x4 acc[7][2];
#pragma unroll
  for (int mi = 0; mi < 7; ++mi) {
    acc[mi][0] = zero;
    acc[mi][1] = zero;
  }

  // A ring-3 rotating pointers
  unsigned short *bAc = &Ahs[0][0], *bA1 = &Ahs[1][0], *bA2 = &Ahs[2][0];
  f32x4 aC0, aC1, aN0, aN1;    // A(t+1) regs / A(t+2) in flight
  s16x8 bE0, bE1, bO0, bO1;    // B frags: even k-half / odd k-half of tile t

  // ---- prologue: A(0)->LDS, aC=A(1), bE=B(kt32=0), bO=B(kt32=1)
  {
    aC0 = *(const f32x4*)(aptr);                   // A(0)
    aC1 = *(const f32x4*)(aptr + 4);
    bE0 = ldsr(bfp);                               // kt32 = 0
    bE1 = ldsr(bfp + 512);
    aN0 = *(const f32x4*)(aptr + 64);              // A(1)
    aN1 = *(const f32x4*)(aptr + 68);
    bO0 = ldsr(bfp + 16384);                       // kt32 = 1
    bO1 = ldsr(bfp + 16384 + 512);
    *(u32x4*)(bAc + awz) = cvt8(aC0, aC1);         // A(0) -> LDS
    aC0 = aN0; aC1 = aN1;
    WAIT_LGKM0();
    __builtin_amdgcn_s_barrier();
  }

  for (int it = 0; it < 31; ++it) {
    // issue A-prefetch, CLAMPED to last tile (at it=30 re-load A(31): no OOB,
    // uniform VMEM count, value unused)
    const int kpre = (it < 30 ? it + 2 : 31) * 64;
    aN0 = *(const f32x4*)(aptr + kpre);
    aN1 = *(const f32x4*)(aptr + kpre + 4);
    const unsigned short* bnext = bfp + (size_t)(it + 1) * 32768;

    // even k-half: 7 A-frags x bE, then reload bE for it+1
    __builtin_amdgcn_s_setprio(1);
#pragma unroll
    for (int mi = 0; mi < 7; ++mi) {
      const s16x8 fah = ldsr(bAc + fa[0][mi]);
      MF(fah, bE0, acc[mi][0]);
      MF(fah, bE1, acc[mi][1]);
    }
    __builtin_amdgcn_s_setprio(0);
    bE0 = ldsr(bnext);                             // kt32 = 2*(it+1)
    bE1 = ldsr(bnext + 512);

    // odd k-half: 7 A-frags x bO, then reload bO for it+1
    __builtin_amdgcn_s_setprio(1);
#pragma unroll
    for (int mi = 0; mi < 7; ++mi) {
      const s16x8 fah = ldsr(bAc + fa[1][mi]);
      MF(fah, bO0, acc[mi][0]);
      MF(fah, bO1, acc[mi][1]);
    }
    __builtin_amdgcn_s_setprio(0);
    bO0 = ldsr(bnext + 16384);                     // kt32 = 2*(it+1)+1
    bO1 = ldsr(bnext + 16384 + 512);

    // A(it+1) cvt + write; ONE barrier per 64-K tile
    *(u32x4*)(bA1 + awz) = cvt8(aC0, aC1);
    aC0 = aN0; aC1 = aN1;
    WAIT_LGKM0();
    __builtin_amdgcn_s_barrier();
    unsigned short* tmp = bAc; bAc = bA1; bA1 = bA2; bA2 = tmp;
  }

  // ---- it = 31 (tail): no staging, no B reload
  {
    __builtin_amdgcn_s_setprio(1);
#pragma unroll
    for (int mi = 0; mi < 7; ++mi) {
      const s16x8 fah = ldsr(bAc + fa[0][mi]);
      MF(fah, bE0, acc[mi][0]);
      MF(fah, bE1, acc[mi][1]);
    }
#pragma unroll
    for (int mi = 0; mi < 7; ++mi) {
      const s16x8 fah = ldsr(bAc + fa[1][mi]);
      MF(fah, bO0, acc[mi][0]);
      MF(fah, bO1, acc[mi][1]);
    }
    __builtin_amdgcn_s_setprio(0);
  }

  // epilogue: s = sum over this wave's 32 cols of relu(acc + att2)*Wf,
  // 16-lane reduce -> att_part[row][w].  C/D: col=lane&15, row=(lane>>4)*4+reg
  const int colL = wn + fr;
  const float wf0 = Wf[colL], wf1 = Wf[colL + 16];
#pragma unroll
  for (int mi = 0; mi < 7; ++mi) {
    const int rowb = m0 + mi * 16 + (q << 2);
#pragma unroll
    for (int r = 0; r < 4; ++r) {
      const int row = rowb + r;
      const int bb = row / P_;
      const float* a2 = att2pb + bb * A_ + colL;
      float s = fmaxf(acc[mi][0][r] + a2[0], 0.f) * wf0
              + fmaxf(acc[mi][1][r] + a2[16], 0.f) * wf1;
#pragma unroll
      for (int off = 1; off < 16; off <<= 1) s += __shfl_xor(s, off);
      if (fr == 0) att_part[row * 16 + w] = s;
    }
  }
}

// ---------------------------------------------------------------------------
// Kernel C: per (b, e-chunk): sum 16 partials -> softmax over P -> alpha,
// awe[b][e] = sum_p alpha[p] * enc[b][p][e].  grid = B*4, block 256
// (512-col chunks, f32x2 loads) for more L3-BW parallelism.
// ---------------------------------------------------------------------------
__global__ void softmax_awe_kernel(const float* __restrict__ enc,
                                   const float* __restrict__ att_part,
                                   float* __restrict__ out) {
  const int bid = blockIdx.x;
  const int b = bid >> 2, ch = bid & 3;
  const int t = threadIdx.x;
  __shared__ float sm[256];
  __shared__ float alpha_s[P_];

  float av = -1e30f;
  if (t < P_) {
    const float* apt = att_part + (b * P_ + t) * 16;
    float s = 0.f;
#pragma unroll
    for (int i = 0; i < 16; ++i) s += apt[i];
    av = s;
  }
  sm[t] = av;
  __syncthreads();
  for (int st = 128; st > 0; st >>= 1) {
    if (t < st) sm[t] = fmaxf(sm[t], sm[t + st]);
    __syncthreads();
  }
  const float mx = sm[0];
  __syncthreads();
  float ev = 0.f;
  if (t < P_) ev = __expf(av - mx);
  sm[t] = ev;
  __syncthreads();
  for (int st = 128; st > 0; st >>= 1) {
    if (t < st) sm[t] += sm[t + st];
    __syncthreads();
  }
  const float denom = sm[0];
  const float al = ev / denom;
  if (t < P_) {
    alpha_s[t] = al;
    if (ch == 0) out[B_ * E_ + b * P_ + t] = al;   // alpha output
  }
  __syncthreads();

  const int e0 = ch * 512 + t * 2;
  const float* ebase = enc + (size_t)b * P_ * E_ + e0;
  f32x2 acc = {0.f, 0.f};
  for (int p = 0; p < P_; ++p) {
    const f32x2 v = *(const f32x2*)(ebase + (size_t)p * E_);
    const float a = alpha_s[p];
    acc.x += a * v.x;
    acc.y += a * v.y;
  }
  *(f32x2*)(out + b * E_ + e0) = acc;
}

// ---------------------------------------------------------------------------
extern "C" void kernel_launch(void* const* d_in, const int* in_sizes, int n_in,
                              void* d_out, int out_size, void* d_ws, size_t ws_size,
                              hipStream_t stream) {
  const float* enc = (const float*)d_in[0];
  const float* h   = (const float*)d_in[1];
  const float* We  = (const float*)d_in[2];
  const float* be  = (const float*)d_in[3];
  const float* Wd  = (const float*)d_in[4];
  const float* bd  = (const float*)d_in[5];
  const float* Wf  = (const float*)d_in[6];
  // d_in[7] = bf: constant shift before softmax -> cancels; unused.
  float* out = (float*)d_out;

  // workspace layout (~3.9 MB)
  float* att2pb = (float*)d_ws;                       // 128*512 f32
  float* att_part = att2pb + B_ * A_;                 // 25088*16 f32
  unsigned short* WeTf = (unsigned short*)(att_part + M_ * 16);  // 64*16384 u16

  we_conv_kernel<<<dim3(A_ / 32, E_ / 32), dim3(32, 32), 0, stream>>>(We, WeTf);
  att2_kernel<<<B_, 256, 0, stream>>>(h, Wd, bd, be, att2pb);
  score_kernel<<<M_ / MT, 1024, 0, stream>>>(enc, WeTf, att2pb, Wf, att_part);
  softmax_awe_kernel<<<B_ * 4, 256, 0, stream>>>(enc, att_part, out);
}